// Round 1
// baseline (4731.685 us; speedup 1.0000x reference)
//
#include <hip/hip_runtime.h>
#include <cstddef>
#include <cstdint>

#define NN 20000
#define EE 160000
#define EPRIME 180000   // EE + NN (self loops)
#define GG 128
#define FF 114
#define HH 10
#define HFD 1140        // FF*HH
#define NJ 18           // ceil(1140/64)

static inline int cdiv(int a, int b) { return (a + b - 1) / b; }

// ---------------- CSR construction ----------------

__global__ void k_init(int* __restrict__ deg, int* __restrict__ gstart, int* __restrict__ gend) {
    int i = blockIdx.x * blockDim.x + threadIdx.x;
    if (i < NN) deg[i] = 1;               // self loop
    if (i < GG) { gstart[i] = NN; gend[i] = 0; }
}

__global__ void k_count(const int* __restrict__ ei, int* __restrict__ deg) {
    int i = blockIdx.x * blockDim.x + threadIdx.x;
    if (i < EE) atomicAdd(&deg[ei[EE + i]], 1);
}

__global__ void k_scan(const int* __restrict__ deg, int* __restrict__ offs) {
    __shared__ int tmp[1024];
    __shared__ int carry;
    int tid = threadIdx.x;
    if (tid == 0) { carry = 0; offs[0] = 0; }
    __syncthreads();
    for (int base = 0; base < NN; base += 1024) {
        int i = base + tid;
        int v = (i < NN) ? deg[i] : 0;
        tmp[tid] = v;
        __syncthreads();
        for (int off = 1; off < 1024; off <<= 1) {
            int t = (tid >= off) ? tmp[tid - off] : 0;
            __syncthreads();
            tmp[tid] += t;
            __syncthreads();
        }
        int incl = tmp[tid];
        int c = carry;
        __syncthreads();
        if (i < NN) offs[i + 1] = c + incl;
        if (tid == 1023) carry = c + incl;
        __syncthreads();
    }
}

__global__ void k_prep(const int* __restrict__ offs, int* __restrict__ cursor,
                       const int* __restrict__ deg, float* __restrict__ dinv,
                       const int* __restrict__ batch, int* __restrict__ gstart, int* __restrict__ gend) {
    int i = blockIdx.x * blockDim.x + threadIdx.x;
    if (i < NN) {
        cursor[i] = offs[i];
        dinv[i] = rsqrtf((float)deg[i]);
        int b = batch[i];
        atomicMin(&gstart[b], i);
        atomicMax(&gend[b], i + 1);
    }
}

__global__ void k_fill(const int* __restrict__ ei, int* __restrict__ cursor, int* __restrict__ csr) {
    int i = blockIdx.x * blockDim.x + threadIdx.x;
    if (i < EPRIME) {
        int s, d;
        if (i < EE) { s = ei[i]; d = ei[EE + i]; }
        else        { s = i - EE; d = s; }
        int pos = atomicAdd(&cursor[d], 1);
        csr[pos] = s;
    }
}

// ---------------- generic fp32 GEMM: C[M,Nc] = A[M,K] @ B[K,Nc] (+bias, +lrelu) ----------------

#define BM 64
#define BN 64
#define BKT 16

__global__ __launch_bounds__(256) void gemm_f32(
    const float* __restrict__ A, const float* __restrict__ B, float* __restrict__ C,
    int M, int Nc, int K, const float* __restrict__ bias, float slope) {
    __shared__ float As[BKT][BM + 4];
    __shared__ float Bs[BKT][BN + 4];
    int tid = threadIdx.x;
    int tx = tid & 15, ty = tid >> 4;
    int row0 = blockIdx.y * BM, col0 = blockIdx.x * BN;
    float acc[4][4] = {};
    for (int kk = 0; kk < K; kk += BKT) {
#pragma unroll
        for (int l = 0; l < 4; ++l) {
            int idx = tid + 256 * l;
            int m = idx >> 4, k = idx & 15;
            int gr = row0 + m, gk = kk + k;
            As[k][m] = (gr < M && gk < K) ? A[(size_t)gr * K + gk] : 0.f;
        }
#pragma unroll
        for (int l = 0; l < 4; ++l) {
            int idx = tid + 256 * l;
            int nn = idx & 63, k = idx >> 6;
            int gc = col0 + nn, gk = kk + k;
            Bs[k][nn] = (gc < Nc && gk < K) ? B[(size_t)gk * Nc + gc] : 0.f;
        }
        __syncthreads();
#pragma unroll
        for (int k = 0; k < BKT; ++k) {
            float4 av = *(const float4*)&As[k][ty * 4];
            float4 bv = *(const float4*)&Bs[k][tx * 4];
            float a[4] = {av.x, av.y, av.z, av.w};
            float b[4] = {bv.x, bv.y, bv.z, bv.w};
#pragma unroll
            for (int i = 0; i < 4; ++i)
#pragma unroll
                for (int j = 0; j < 4; ++j) acc[i][j] += a[i] * b[j];
        }
        __syncthreads();
    }
#pragma unroll
    for (int i = 0; i < 4; ++i) {
        int r = row0 + ty * 4 + i;
        if (r >= M) continue;
#pragma unroll
        for (int j = 0; j < 4; ++j) {
            int c = col0 + tx * 4 + j;
            if (c >= Nc) continue;
            float v = acc[i][j];
            if (bias) v += bias[c];
            if (slope >= 0.f) v = (v >= 0.f) ? v : slope * v;
            C[(size_t)r * Nc + c] = v;
        }
    }
}

// ---------------- attention logits: a_s/a_d [N,H] ----------------

__global__ void k_att(const float* __restrict__ h0, const float* __restrict__ att_src,
                      const float* __restrict__ att_dst, float* __restrict__ as_, float* __restrict__ ad_) {
    int id = blockIdx.x * blockDim.x + threadIdx.x;
    if (id >= NN * HH) return;
    int n = id / HH, h = id % HH;
    const float* row = h0 + (size_t)n * HFD + h * FF;
    const float* ws = att_src + h * FF;
    const float* wd = att_dst + h * FF;
    float as = 0.f, ad = 0.f;
    for (int f = 0; f < FF; ++f) {
        float v = row[f];
        as += v * ws[f];
        ad += v * wd[f];
    }
    as_[id] = as;
    ad_[id] = ad;
}

// ---------------- GAT aggregation: one wave per dst node ----------------

__global__ __launch_bounds__(256) void gat_agg(
    const float* __restrict__ h0, const float* __restrict__ as_, const float* __restrict__ ad_,
    const int* __restrict__ offs, const int* __restrict__ csr,
    const float* __restrict__ bias, float* __restrict__ out) {
    int lane = threadIdx.x & 63;
    int n = blockIdx.x * 4 + (threadIdx.x >> 6);
    if (n >= NN) return;
    int beg = offs[n], end = offs[n + 1];
    float my_ad = (lane < HH) ? ad_[n * HH + lane] : 0.f;

    int headj[NJ];
#pragma unroll
    for (int j = 0; j < NJ; ++j) headj[j] = (lane + 64 * j) / FF;  // ok: lanes with k>=1140 get 10, unused

    // pass 1: per-head max (lanes 0..9)
    float mymax = -1e30f;
    for (int e = beg; e < end; ++e) {
        int s = csr[e];
        if (lane < HH) {
            float t = as_[s * HH + lane] + my_ad;
            t = (t >= 0.f) ? t : 0.2f * t;
            mymax = fmaxf(mymax, t);
        }
    }

    // pass 2: exp/den + unnormalized feature accumulation
    float den = 0.f;
    float acc[NJ];
#pragma unroll
    for (int j = 0; j < NJ; ++j) acc[j] = 0.f;

    for (int e = beg; e < end; ++e) {
        int s = csr[e];
        float ex = 0.f;
        if (lane < HH) {
            float t = as_[s * HH + lane] + my_ad;
            t = (t >= 0.f) ? t : 0.2f * t;
            ex = __expf(t - mymax);
            den += ex;
        }
        const float* hrow = h0 + (size_t)s * HFD;
#pragma unroll
        for (int j = 0; j < NJ - 1; ++j) {
            float w = __shfl(ex, headj[j], 64);
            acc[j] += w * hrow[lane + 64 * j];
        }
        {
            float w = __shfl(ex, headj[NJ - 1], 64);
            if (lane < HFD - 64 * (NJ - 1)) acc[NJ - 1] += w * hrow[lane + 64 * (NJ - 1)];
        }
    }

#pragma unroll
    for (int j = 0; j < NJ; ++j) {
        int k = lane + 64 * j;
        float d = __shfl(den, headj[j], 64);
        if (k < HFD) {
            float v = acc[j] / d + bias[k];
            out[(size_t)n * HFD + k] = (v >= 0.f) ? v : 0.01f * v;
        }
    }
}

// ---------------- GCN aggregation: one wave per dst node ----------------

__global__ __launch_bounds__(256) void gcn_agg(
    const float* __restrict__ h2, const int* __restrict__ offs, const int* __restrict__ csr,
    const float* __restrict__ dinv, const float* __restrict__ bias, float* __restrict__ out) {
    int lane = threadIdx.x & 63;
    int n = blockIdx.x * 4 + (threadIdx.x >> 6);
    if (n >= NN) return;
    int beg = offs[n], end = offs[n + 1];
    float di = dinv[n];
    float acc[NJ];
#pragma unroll
    for (int j = 0; j < NJ; ++j) acc[j] = 0.f;

    for (int e = beg; e < end; ++e) {
        int s = csr[e];
        float w = dinv[s] * di;
        const float* hrow = h2 + (size_t)s * HFD;
#pragma unroll
        for (int j = 0; j < NJ - 1; ++j) acc[j] += w * hrow[lane + 64 * j];
        if (lane < HFD - 64 * (NJ - 1)) acc[NJ - 1] += w * hrow[lane + 64 * (NJ - 1)];
    }

#pragma unroll
    for (int j = 0; j < NJ; ++j) {
        int k = lane + 64 * j;
        if (k < HFD) {
            float v = acc[j] + bias[k];
            out[(size_t)n * HFD + k] = (v >= 0.f) ? v : 0.01f * v;
        }
    }
}

// ---------------- graph pooling (max + mean) ----------------

__global__ void k_pool(const float* __restrict__ hfeat, const int* __restrict__ gs,
                       const int* __restrict__ ge, float* __restrict__ gout) {
    int g = blockIdx.x;
    int s = gs[g], e = ge[g];
    int cnt = e - s;
    for (int col = threadIdx.x; col < HFD; col += blockDim.x) {
        float mx = -1e30f, sm = 0.f;
        for (int r = s; r < e; ++r) {
            float v = hfeat[(size_t)r * HFD + col];
            mx = fmaxf(mx, v);
            sm += v;
        }
        float mean;
        if (cnt <= 0) { mx = 0.f; mean = 0.f; }
        else mean = sm / (float)cnt;
        gout[(size_t)g * (2 * HFD) + col] = mx;
        gout[(size_t)g * (2 * HFD) + HFD + col] = mean;
    }
}

// ---------------- fcg2: [G,1000] @ [1000,64] + b ----------------

__global__ void k_fcg2(const float* __restrict__ in, const float* __restrict__ W,
                       const float* __restrict__ b, float* __restrict__ out) {
    int g = blockIdx.x;
    int o = threadIdx.x;  // 64
    const float* row = in + (size_t)g * 1000;
    float acc = 0.f;
    for (int k = 0; k < 1000; ++k) acc += row[k] * W[k * 64 + o];
    out[(size_t)g * 64 + o] = acc + b[o];
}

// ---------------- final head: xt + fc1 + fc2 + out ----------------

__global__ __launch_bounds__(256) void k_final(
    const float* __restrict__ b1, const float* __restrict__ b2, const float* __restrict__ target,
    const float* __restrict__ fcxtW, const float* __restrict__ fcxtb,
    const float* __restrict__ fc1W, const float* __restrict__ fc1b,
    const float* __restrict__ fc2W, const float* __restrict__ fc2b,
    const float* __restrict__ outW, const float* __restrict__ outb,
    float* __restrict__ out) {
    __shared__ float xc[256];
    __shared__ float y1[128];
    __shared__ float y2[32];
    int g = blockIdx.x, t = threadIdx.x;
    if (t < 64) xc[t] = b1[(size_t)g * 64 + t];
    else if (t < 128) xc[t] = b2[(size_t)g * 64 + (t - 64)];
    if (t < 128) {
        float acc = 0.f;
        const float* trow = target + (size_t)g * 1000;
        for (int k = 0; k < 1000; ++k) acc += trow[k] * fcxtW[k * 128 + t];
        xc[128 + t] = acc + fcxtb[t];
    }
    __syncthreads();
    if (t < 128) {
        float acc = 0.f;
        for (int k = 0; k < 256; ++k) acc += xc[k] * fc1W[k * 128 + t];
        acc += fc1b[t];
        y1[t] = (acc >= 0.f) ? acc : 0.01f * acc;
    }
    __syncthreads();
    if (t < 32) {
        float acc = 0.f;
        for (int k = 0; k < 128; ++k) acc += y1[k] * fc2W[k * 32 + t];
        acc += fc2b[t];
        y2[t] = (acc >= 0.f) ? acc : 0.01f * acc;
    }
    __syncthreads();
    if (t == 0) {
        float acc = 0.f;
        for (int k = 0; k < 32; ++k) acc += y2[k] * outW[k];
        out[g] = acc + outb[0];
    }
}

// ---------------- host launch ----------------

extern "C" void kernel_launch(void* const* d_in, const int* in_sizes, int n_in,
                              void* d_out, int out_size, void* d_ws, size_t ws_size,
                              hipStream_t stream) {
    (void)in_sizes; (void)n_in; (void)out_size; (void)ws_size;

    // workspace carve
    size_t off = 0;
    auto alloc = [&](size_t bytes) -> void* {
        void* p = (char*)d_ws + off;
        off += (bytes + 255) & ~(size_t)255;
        return p;
    };
    float* bufA   = (float*)alloc((size_t)NN * HFD * 4);
    float* bufB   = (float*)alloc((size_t)NN * HFD * 4);
    float* a_s    = (float*)alloc((size_t)NN * HH * 4);
    float* a_d    = (float*)alloc((size_t)NN * HH * 4);
    int*   deg    = (int*)alloc((size_t)NN * 4);
    int*   offs   = (int*)alloc((size_t)(NN + 1) * 4);
    int*   cursor = (int*)alloc((size_t)NN * 4);
    int*   csr    = (int*)alloc((size_t)EPRIME * 4);
    float* dinv   = (float*)alloc((size_t)NN * 4);
    int*   gstart = (int*)alloc((size_t)GG * 4);
    int*   gend   = (int*)alloc((size_t)GG * 4);
    float* gpool  = (float*)alloc((size_t)GG * 2 * HFD * 4);
    float* fc1out = (float*)alloc((size_t)GG * 1000 * 4);
    float* bout   = (float*)alloc((size_t)2 * GG * 64 * 4);

    const float* target = (const float*)d_in[6];

    for (int b = 0; b < 2; ++b) {
        const float* x     = (const float*)d_in[b ? 3 : 0];
        const int*   ei    = (const int*)d_in[b ? 4 : 1];
        const int*   batch = (const int*)d_in[b ? 5 : 2];
        int pb = 7 + b * 10;
        const float* gatW    = (const float*)d_in[pb + 0];
        const float* att_src = (const float*)d_in[pb + 1];
        const float* att_dst = (const float*)d_in[pb + 2];
        const float* gatb    = (const float*)d_in[pb + 3];
        const float* gcnW    = (const float*)d_in[pb + 4];
        const float* gcnb    = (const float*)d_in[pb + 5];
        const float* f1W     = (const float*)d_in[pb + 6];
        const float* f1b     = (const float*)d_in[pb + 7];
        const float* f2W     = (const float*)d_in[pb + 8];
        const float* f2b     = (const float*)d_in[pb + 9];

        hipLaunchKernelGGL(k_init, dim3(cdiv(NN, 256)), dim3(256), 0, stream, deg, gstart, gend);
        hipLaunchKernelGGL(k_count, dim3(cdiv(EE, 256)), dim3(256), 0, stream, ei, deg);
        hipLaunchKernelGGL(k_scan, dim3(1), dim3(1024), 0, stream, deg, offs);
        hipLaunchKernelGGL(k_prep, dim3(cdiv(NN, 256)), dim3(256), 0, stream,
                           offs, cursor, deg, dinv, batch, gstart, gend);
        hipLaunchKernelGGL(k_fill, dim3(cdiv(EPRIME, 256)), dim3(256), 0, stream, ei, cursor, csr);

        // h0 = x @ gatW   [N,114]@[114,1140]
        hipLaunchKernelGGL(gemm_f32, dim3(cdiv(HFD, BN), cdiv(NN, BM)), dim3(256), 0, stream,
                           x, gatW, bufA, NN, HFD, FF, (const float*)nullptr, -1.f);
        // attention logits
        hipLaunchKernelGGL(k_att, dim3(cdiv(NN * HH, 256)), dim3(256), 0, stream,
                           bufA, att_src, att_dst, a_s, a_d);
        // GAT aggregate -> bufB (lrelu 0.01 fused)
        hipLaunchKernelGGL(gat_agg, dim3(cdiv(NN, 4)), dim3(256), 0, stream,
                           bufA, a_s, a_d, offs, csr, gatb, bufB);
        // h2 = h1 @ gcnW  [N,1140]@[1140,1140]
        hipLaunchKernelGGL(gemm_f32, dim3(cdiv(HFD, BN), cdiv(NN, BM)), dim3(256), 0, stream,
                           bufB, gcnW, bufA, NN, HFD, HFD, (const float*)nullptr, -1.f);
        // GCN aggregate -> bufB (lrelu 0.01 fused)
        hipLaunchKernelGGL(gcn_agg, dim3(cdiv(NN, 4)), dim3(256), 0, stream,
                           bufA, offs, csr, dinv, gcnb, bufB);
        // pooling
        hipLaunchKernelGGL(k_pool, dim3(GG), dim3(256), 0, stream, bufB, gstart, gend, gpool);
        // fcg1: [G,2280]@[2280,1000] + bias + lrelu
        hipLaunchKernelGGL(gemm_f32, dim3(cdiv(1000, BN), cdiv(GG, BM)), dim3(256), 0, stream,
                           gpool, f1W, fc1out, GG, 1000, 2 * HFD, f1b, 0.01f);
        // fcg2: [G,1000]@[1000,64] + bias
        hipLaunchKernelGGL(k_fcg2, dim3(GG), dim3(64), 0, stream,
                           fc1out, f2W, f2b, bout + (size_t)b * GG * 64);
    }

    hipLaunchKernelGGL(k_final, dim3(GG), dim3(256), 0, stream,
                       bout, bout + (size_t)GG * 64, target,
                       (const float*)d_in[27], (const float*)d_in[28],
                       (const float*)d_in[29], (const float*)d_in[30],
                       (const float*)d_in[31], (const float*)d_in[32],
                       (const float*)d_in[33], (const float*)d_in[34],
                       (float*)d_out);
}

// Round 2
// 2722.398 us; speedup vs baseline: 1.7381x; 1.7381x over previous
//
#include <hip/hip_runtime.h>
#include <cstddef>
#include <cstdint>

#define NN 20000
#define EE 160000
#define EPRIME 180000   // EE + NN (self loops)
#define GG 128
#define FF 114
#define HH 10
#define HFD 1140        // FF*HH
#define NJ 18           // 1152/64
#define KP 1152         // padded feature dim (36*32, 9*128)

typedef unsigned short ushort_t;
typedef __attribute__((ext_vector_type(8))) short bf16x8;
typedef __attribute__((ext_vector_type(4))) float f32x4;

static inline int cdiv(int a, int b) { return (a + b - 1) / b; }

// ---------------- bf16 helpers ----------------

__device__ __forceinline__ ushort_t f2bf(float v) {
    union { float f; unsigned u; } c; c.f = v;
    unsigned u = c.u;
    unsigned r = (u + 0x7fffu + ((u >> 16) & 1u)) >> 16;   // RNE
    return (ushort_t)r;
}
__device__ __forceinline__ float bf2f(ushort_t h) {
    union { unsigned u; float f; } c; c.u = ((unsigned)h) << 16;
    return c.f;
}

__device__ __forceinline__ void gload16(const void* g, const ushort_t* l) {
    __builtin_amdgcn_global_load_lds(
        (const __attribute__((address_space(1))) unsigned int*)g,
        (__attribute__((address_space(3))) unsigned int*)l, 16, 0, 0);
}

// ---------------- CSR construction ----------------

__global__ void k_init(int* __restrict__ deg, int* __restrict__ gstart, int* __restrict__ gend) {
    int i = blockIdx.x * blockDim.x + threadIdx.x;
    if (i < NN) deg[i] = 1;               // self loop
    if (i < GG) { gstart[i] = NN; gend[i] = 0; }
}

__global__ void k_count(const int* __restrict__ ei, int* __restrict__ deg) {
    int i = blockIdx.x * blockDim.x + threadIdx.x;
    if (i < EE) atomicAdd(&deg[ei[EE + i]], 1);
}

__global__ void k_scan(const int* __restrict__ deg, int* __restrict__ offs) {
    __shared__ int tmp[1024];
    __shared__ int carry;
    int tid = threadIdx.x;
    if (tid == 0) { carry = 0; offs[0] = 0; }
    __syncthreads();
    for (int base = 0; base < NN; base += 1024) {
        int i = base + tid;
        int v = (i < NN) ? deg[i] : 0;
        tmp[tid] = v;
        __syncthreads();
        for (int off = 1; off < 1024; off <<= 1) {
            int t = (tid >= off) ? tmp[tid - off] : 0;
            __syncthreads();
            tmp[tid] += t;
            __syncthreads();
        }
        int incl = tmp[tid];
        int c = carry;
        __syncthreads();
        if (i < NN) offs[i + 1] = c + incl;
        if (tid == 1023) carry = c + incl;
        __syncthreads();
    }
}

__global__ void k_prep(const int* __restrict__ offs, int* __restrict__ cursor,
                       const int* __restrict__ deg, float* __restrict__ dinv,
                       const int* __restrict__ batch, int* __restrict__ gstart, int* __restrict__ gend) {
    int i = blockIdx.x * blockDim.x + threadIdx.x;
    if (i < NN) {
        cursor[i] = offs[i];
        dinv[i] = rsqrtf((float)deg[i]);
        int b = batch[i];
        atomicMin(&gstart[b], i);
        atomicMax(&gend[b], i + 1);
    }
}

__global__ void k_fill(const int* __restrict__ ei, int* __restrict__ cursor, int* __restrict__ csr) {
    int i = blockIdx.x * blockDim.x + threadIdx.x;
    if (i < EPRIME) {
        int s, d;
        if (i < EE) { s = ei[i]; d = ei[EE + i]; }
        else        { s = i - EE; d = s; }
        int pos = atomicAdd(&cursor[d], 1);
        csr[pos] = s;
    }
}

// ---------------- split / transpose-split conversions ----------------

// x [NN,FF] fp32 -> xhi/xlo [NN,128] bf16 (zero pad k>=FF)
__global__ void k_split_x(const float* __restrict__ x, ushort_t* __restrict__ xhi, ushort_t* __restrict__ xlo) {
    int idx = blockIdx.x * 256 + threadIdx.x;
    if (idx >= NN * 128) return;
    int n = idx >> 7, k = idx & 127;
    float v = (k < FF) ? x[(size_t)n * FF + k] : 0.f;
    ushort_t hi = f2bf(v);
    ushort_t lo = f2bf(v - bf2f(hi));
    xhi[idx] = hi; xlo[idx] = lo;
}

// W [K,Nc] fp32 -> T[n,k] = W[k,n], split bf16, zero pad. T is [Npad][Kpad].
__global__ void k_tsplit(const float* __restrict__ W, int K, int Nc, int Kpad, int Npad,
                         ushort_t* __restrict__ Thi, ushort_t* __restrict__ Tlo) {
    int idx = blockIdx.x * 256 + threadIdx.x;
    if (idx >= Npad * Kpad) return;
    int n = idx / Kpad, k = idx % Kpad;
    float v = (n < Nc && k < K) ? W[(size_t)k * Nc + n] : 0.f;
    ushort_t hi = f2bf(v);
    ushort_t lo = f2bf(v - bf2f(hi));
    Thi[idx] = hi; Tlo[idx] = lo;
}

// ---------------- split-bf16 MFMA GEMM ----------------
// C[M x Nreal] = (Ahi+Alo)[M x K] @ (Bthi+Btlo)^T   (Bt stored [Npad][Kpad])
// OUTMODE 0: fp32 C (ldc), guard c<Nreal. OUTMODE 1: split pair Chi/Clo (ldcs=KP), full width.

template <int OUTMODE>
__global__ __launch_bounds__(256) void mfma_gemm(
    const ushort_t* __restrict__ Ahi, const ushort_t* __restrict__ Alo,
    const ushort_t* __restrict__ Bthi, const ushort_t* __restrict__ Btlo,
    int lda, int ldb, int M, int Nreal, int ksteps,
    float* __restrict__ C, int ldc,
    ushort_t* __restrict__ Chi, ushort_t* __restrict__ Clo, int ldcs) {
    __shared__ __align__(16) ushort_t lds[4 * 4096];   // planes: Ahi, Alo, Bhi, Blo ([4 kg][128 row][8])
    const int tid = threadIdx.x;
    const int lane = tid & 63;
    const int w = tid >> 6;
    const int wr = w >> 1, wc = w & 1;
    int row0 = blockIdx.y * 128; if (row0 > M - 128) row0 = M - 128;   // overlap trick, idempotent writes
    const int col0 = blockIdx.x * 128;

    f32x4 acc[4][4];
#pragma unroll
    for (int i = 0; i < 4; ++i)
#pragma unroll
        for (int j = 0; j < 4; ++j) acc[i][j] = (f32x4){0.f, 0.f, 0.f, 0.f};

    const size_t ldaB = (size_t)lda * 2, ldbB = (size_t)ldb * 2;
    const char* pAhi[2]; const char* pAlo[2]; const char* pBhi[2]; const char* pBlo[2];
    unsigned ldsoff[2];
#pragma unroll
    for (int i = 0; i < 2; ++i) {
        int c = (w * 2 + i) * 64 + lane;
        int kg = c >> 7, r = c & 127;
        pAhi[i] = (const char*)Ahi + (size_t)(row0 + r) * ldaB + kg * 16;
        pAlo[i] = (const char*)Alo + (size_t)(row0 + r) * ldaB + kg * 16;
        pBhi[i] = (const char*)Bthi + (size_t)(col0 + r) * ldbB + kg * 16;
        pBlo[i] = (const char*)Btlo + (size_t)(col0 + r) * ldbB + kg * 16;
        ldsoff[i] = (w * 2 + i) * 512;
    }
    const int kgf = lane >> 4, r15 = lane & 15;

    for (int ks = 0; ks < ksteps; ++ks) {
        size_t kb = (size_t)ks * 64;
#pragma unroll
        for (int i = 0; i < 2; ++i) {
            gload16(pAhi[i] + kb, lds + 0 * 4096 + ldsoff[i]);
            gload16(pAlo[i] + kb, lds + 1 * 4096 + ldsoff[i]);
            gload16(pBhi[i] + kb, lds + 2 * 4096 + ldsoff[i]);
            gload16(pBlo[i] + kb, lds + 3 * 4096 + ldsoff[i]);
        }
        asm volatile("s_waitcnt vmcnt(0)" ::: "memory");
        __syncthreads();
        bf16x8 ah[4], al[4], bh[4], bl[4];
#pragma unroll
        for (int i = 0; i < 4; ++i) {
            int ra = wr * 64 + i * 16 + r15;
            int rb = wc * 64 + i * 16 + r15;
            ah[i] = *(const bf16x8*)(lds + 0 * 4096 + kgf * 1024 + ra * 8);
            al[i] = *(const bf16x8*)(lds + 1 * 4096 + kgf * 1024 + ra * 8);
            bh[i] = *(const bf16x8*)(lds + 2 * 4096 + kgf * 1024 + rb * 8);
            bl[i] = *(const bf16x8*)(lds + 3 * 4096 + kgf * 1024 + rb * 8);
        }
#pragma unroll
        for (int i = 0; i < 4; ++i)
#pragma unroll
            for (int j = 0; j < 4; ++j) {
                acc[i][j] = __builtin_amdgcn_mfma_f32_16x16x32_bf16(ah[i], bh[j], acc[i][j], 0, 0, 0);
                acc[i][j] = __builtin_amdgcn_mfma_f32_16x16x32_bf16(ah[i], bl[j], acc[i][j], 0, 0, 0);
                acc[i][j] = __builtin_amdgcn_mfma_f32_16x16x32_bf16(al[i], bh[j], acc[i][j], 0, 0, 0);
            }
        __syncthreads();
    }

    const int g4 = lane >> 4;
#pragma unroll
    for (int i = 0; i < 4; ++i)
#pragma unroll
        for (int j = 0; j < 4; ++j) {
            int c = col0 + wc * 64 + j * 16 + r15;
#pragma unroll
            for (int reg = 0; reg < 4; ++reg) {
                int r = row0 + wr * 64 + i * 16 + g4 * 4 + reg;
                float v = acc[i][j][reg];
                if (OUTMODE == 0) {
                    if (r < M && c < Nreal) C[(size_t)r * ldc + c] = v;
                } else {
                    if (r < M) {
                        if (c >= Nreal) v = 0.f;
                        ushort_t hi = f2bf(v);
                        ushort_t lo = f2bf(v - bf2f(hi));
                        Chi[(size_t)r * ldcs + c] = hi;
                        Clo[(size_t)r * ldcs + c] = lo;
                    }
                }
            }
        }
}

// ---------------- attention logits from split h0 ----------------

__global__ void k_att(const ushort_t* __restrict__ h0hi, const ushort_t* __restrict__ h0lo,
                      const float* __restrict__ att_src, const float* __restrict__ att_dst,
                      float* __restrict__ as_, float* __restrict__ ad_) {
    int id = blockIdx.x * blockDim.x + threadIdx.x;
    if (id >= NN * HH) return;
    int n = id / HH, h = id % HH;
    const ushort_t* rh = h0hi + (size_t)n * KP + h * FF;
    const ushort_t* rl = h0lo + (size_t)n * KP + h * FF;
    const float* ws = att_src + h * FF;
    const float* wd = att_dst + h * FF;
    float as = 0.f, ad = 0.f;
    for (int f = 0; f < FF; ++f) {
        float v = bf2f(rh[f]) + bf2f(rl[f]);
        as += v * ws[f];
        ad += v * wd[f];
    }
    as_[id] = as;
    ad_[id] = ad;
}

// ---------------- GAT aggregation: one wave per dst node (split in/out) ----------------

__global__ __launch_bounds__(256) void gat_agg(
    const ushort_t* __restrict__ h0hi, const ushort_t* __restrict__ h0lo,
    const float* __restrict__ as_, const float* __restrict__ ad_,
    const int* __restrict__ offs, const int* __restrict__ csr,
    const float* __restrict__ bias,
    ushort_t* __restrict__ outhi, ushort_t* __restrict__ outlo) {
    int lane = threadIdx.x & 63;
    int n = blockIdx.x * 4 + (threadIdx.x >> 6);
    if (n >= NN) return;
    int beg = offs[n], end = offs[n + 1];
    float my_ad = (lane < HH) ? ad_[n * HH + lane] : 0.f;

    int headj[NJ];
#pragma unroll
    for (int j = 0; j < NJ; ++j) headj[j] = (lane + 64 * j) / FF;  // 10 for pad lanes (ex=0 there)

    float mymax = -1e30f;
    for (int e = beg; e < end; ++e) {
        int s = csr[e];
        if (lane < HH) {
            float t = as_[s * HH + lane] + my_ad;
            t = (t >= 0.f) ? t : 0.2f * t;
            mymax = fmaxf(mymax, t);
        }
    }

    float den = 0.f;
    float acc[NJ];
#pragma unroll
    for (int j = 0; j < NJ; ++j) acc[j] = 0.f;

    for (int e = beg; e < end; ++e) {
        int s = csr[e];
        float ex = 0.f;
        if (lane < HH) {
            float t = as_[s * HH + lane] + my_ad;
            t = (t >= 0.f) ? t : 0.2f * t;
            ex = __expf(t - mymax);
            den += ex;
        }
        const ushort_t* hh = h0hi + (size_t)s * KP;
        const ushort_t* hl = h0lo + (size_t)s * KP;
#pragma unroll
        for (int j = 0; j < NJ; ++j) {
            float w = __shfl(ex, headj[j], 64);
            int k = lane + 64 * j;
            acc[j] += w * (bf2f(hh[k]) + bf2f(hl[k]));
        }
    }

#pragma unroll
    for (int j = 0; j < NJ; ++j) {
        int k = lane + 64 * j;
        float d = __shfl(den, headj[j], 64);
        float v = 0.f;
        if (k < HFD) {
            v = acc[j] / d + bias[k];
            v = (v >= 0.f) ? v : 0.01f * v;
        }
        ushort_t hi = f2bf(v);
        ushort_t lo = f2bf(v - bf2f(hi));
        outhi[(size_t)n * KP + k] = hi;
        outlo[(size_t)n * KP + k] = lo;
    }
}

// ---------------- GCN aggregation: one wave per dst node (fp32 in/out) ----------------

__global__ __launch_bounds__(256) void gcn_agg(
    const float* __restrict__ h2, const int* __restrict__ offs, const int* __restrict__ csr,
    const float* __restrict__ dinv, const float* __restrict__ bias, float* __restrict__ out) {
    int lane = threadIdx.x & 63;
    int n = blockIdx.x * 4 + (threadIdx.x >> 6);
    if (n >= NN) return;
    int beg = offs[n], end = offs[n + 1];
    float di = dinv[n];
    float acc[NJ];
#pragma unroll
    for (int j = 0; j < NJ; ++j) acc[j] = 0.f;

    for (int e = beg; e < end; ++e) {
        int s = csr[e];
        float w = dinv[s] * di;
        const float* hrow = h2 + (size_t)s * HFD;
#pragma unroll
        for (int j = 0; j < NJ - 1; ++j) acc[j] += w * hrow[lane + 64 * j];
        if (lane < HFD - 64 * (NJ - 1)) acc[NJ - 1] += w * hrow[lane + 64 * (NJ - 1)];
    }

#pragma unroll
    for (int j = 0; j < NJ; ++j) {
        int k = lane + 64 * j;
        if (k < HFD) {
            float v = acc[j] + bias[k];
            out[(size_t)n * HFD + k] = (v >= 0.f) ? v : 0.01f * v;
        }
    }
}

// ---------------- graph pooling (max + mean), row-coalesced ----------------

__global__ void k_pool(const float* __restrict__ hfeat, const int* __restrict__ gs,
                       const int* __restrict__ ge, float* __restrict__ gout) {
    int g = blockIdx.x;
    int col = blockIdx.y * 228 + threadIdx.x;
    if (threadIdx.x >= 228) return;
    int s = gs[g], e = ge[g];
    int cnt = e - s;
    float mx = -1e30f, sm = 0.f;
    for (int r = s; r < e; ++r) {
        float v = hfeat[(size_t)r * HFD + col];
        mx = fmaxf(mx, v);
        sm += v;
    }
    float mean;
    if (cnt <= 0) { mx = 0.f; mean = 0.f; }
    else mean = sm / (float)cnt;
    gout[(size_t)g * (2 * HFD) + col] = mx;
    gout[(size_t)g * (2 * HFD) + HFD + col] = mean;
}

// ---------------- generic fp32 GEMM (small layers only) ----------------

#define BM 64
#define BN 64
#define BKT 16

__global__ __launch_bounds__(256) void gemm_f32(
    const float* __restrict__ A, const float* __restrict__ B, float* __restrict__ C,
    int M, int Nc, int K, const float* __restrict__ bias, float slope) {
    __shared__ float As[BKT][BM + 4];
    __shared__ float Bs[BKT][BN + 4];
    int tid = threadIdx.x;
    int tx = tid & 15, ty = tid >> 4;
    int row0 = blockIdx.y * BM, col0 = blockIdx.x * BN;
    float acc[4][4] = {};
    for (int kk = 0; kk < K; kk += BKT) {
#pragma unroll
        for (int l = 0; l < 4; ++l) {
            int idx = tid + 256 * l;
            int m = idx >> 4, k = idx & 15;
            int gr = row0 + m, gk = kk + k;
            As[k][m] = (gr < M && gk < K) ? A[(size_t)gr * K + gk] : 0.f;
        }
#pragma unroll
        for (int l = 0; l < 4; ++l) {
            int idx = tid + 256 * l;
            int nn = idx & 63, k = idx >> 6;
            int gc = col0 + nn, gk = kk + k;
            Bs[k][nn] = (gc < Nc && gk < K) ? B[(size_t)gk * Nc + gc] : 0.f;
        }
        __syncthreads();
#pragma unroll
        for (int k = 0; k < BKT; ++k) {
            float4 av = *(const float4*)&As[k][ty * 4];
            float4 bv = *(const float4*)&Bs[k][tx * 4];
            float a[4] = {av.x, av.y, av.z, av.w};
            float b[4] = {bv.x, bv.y, bv.z, bv.w};
#pragma unroll
            for (int i = 0; i < 4; ++i)
#pragma unroll
                for (int j = 0; j < 4; ++j) acc[i][j] += a[i] * b[j];
        }
        __syncthreads();
    }
#pragma unroll
    for (int i = 0; i < 4; ++i) {
        int r = row0 + ty * 4 + i;
        if (r >= M) continue;
#pragma unroll
        for (int j = 0; j < 4; ++j) {
            int c = col0 + tx * 4 + j;
            if (c >= Nc) continue;
            float v = acc[i][j];
            if (bias) v += bias[c];
            if (slope >= 0.f) v = (v >= 0.f) ? v : slope * v;
            C[(size_t)r * Nc + c] = v;
        }
    }
}

// ---------------- fcg2: [G,1000] @ [1000,64] + b ----------------

__global__ void k_fcg2(const float* __restrict__ in, const float* __restrict__ W,
                       const float* __restrict__ b, float* __restrict__ out) {
    int g = blockIdx.x;
    int o = threadIdx.x;  // 64
    const float* row = in + (size_t)g * 1000;
    float acc = 0.f;
    for (int k = 0; k < 1000; ++k) acc += row[k] * W[k * 64 + o];
    out[(size_t)g * 64 + o] = acc + b[o];
}

// ---------------- final head ----------------

__global__ __launch_bounds__(256) void k_final(
    const float* __restrict__ b1, const float* __restrict__ b2, const float* __restrict__ target,
    const float* __restrict__ fcxtW, const float* __restrict__ fcxtb,
    const float* __restrict__ fc1W, const float* __restrict__ fc1b,
    const float* __restrict__ fc2W, const float* __restrict__ fc2b,
    const float* __restrict__ outW, const float* __restrict__ outb,
    float* __restrict__ out) {
    __shared__ float xc[256];
    __shared__ float y1[128];
    __shared__ float y2[32];
    int g = blockIdx.x, t = threadIdx.x;
    if (t < 64) xc[t] = b1[(size_t)g * 64 + t];
    else if (t < 128) xc[t] = b2[(size_t)g * 64 + (t - 64)];
    if (t < 128) {
        float acc = 0.f;
        const float* trow = target + (size_t)g * 1000;
        for (int k = 0; k < 1000; ++k) acc += trow[k] * fcxtW[k * 128 + t];
        xc[128 + t] = acc + fcxtb[t];
    }
    __syncthreads();
    if (t < 128) {
        float acc = 0.f;
        for (int k = 0; k < 256; ++k) acc += xc[k] * fc1W[k * 128 + t];
        acc += fc1b[t];
        y1[t] = (acc >= 0.f) ? acc : 0.01f * acc;
    }
    __syncthreads();
    if (t < 32) {
        float acc = 0.f;
        for (int k = 0; k < 128; ++k) acc += y1[k] * fc2W[k * 32 + t];
        acc += fc2b[t];
        y2[t] = (acc >= 0.f) ? acc : 0.01f * acc;
    }
    __syncthreads();
    if (t == 0) {
        float acc = 0.f;
        for (int k = 0; k < 32; ++k) acc += y2[k] * outW[k];
        out[g] = acc + outb[0];
    }
}

// ---------------- host launch ----------------

extern "C" void kernel_launch(void* const* d_in, const int* in_sizes, int n_in,
                              void* d_out, int out_size, void* d_ws, size_t ws_size,
                              hipStream_t stream) {
    (void)in_sizes; (void)n_in; (void)out_size; (void)ws_size;

    size_t off = 0;
    auto alloc = [&](size_t bytes) -> void* {
        void* p = (char*)d_ws + off;
        off += (bytes + 255) & ~(size_t)255;
        return p;
    };
    // two big overlay regions (each >= max(split pair 92.16MB, fp32 91.2MB))
    char* regionA = (char*)alloc((size_t)2 * NN * KP * 2);
    char* regionB = (char*)alloc((size_t)2 * NN * KP * 2);
    ushort_t* Bthi = (ushort_t*)alloc((size_t)KP * KP * 2);
    ushort_t* Btlo = (ushort_t*)alloc((size_t)KP * KP * 2);
    float* a_s    = (float*)alloc((size_t)NN * HH * 4);
    float* a_d    = (float*)alloc((size_t)NN * HH * 4);
    int*   deg    = (int*)alloc((size_t)NN * 4);
    int*   offs   = (int*)alloc((size_t)(NN + 1) * 4);
    int*   cursor = (int*)alloc((size_t)NN * 4);
    int*   csr    = (int*)alloc((size_t)EPRIME * 4);
    float* dinv   = (float*)alloc((size_t)NN * 4);
    int*   gstart = (int*)alloc((size_t)GG * 4);
    int*   gend   = (int*)alloc((size_t)GG * 4);
    float* gpool  = (float*)alloc((size_t)GG * 2 * HFD * 4);
    float* fc1out = (float*)alloc((size_t)GG * 1000 * 4);
    float* bout   = (float*)alloc((size_t)2 * GG * 64 * 4);

    // overlays
    ushort_t* h0hi = (ushort_t*)regionA;
    ushort_t* h0lo = (ushort_t*)regionA + (size_t)NN * KP;
    float*    h2f  = (float*)regionA;                        // after h0 is dead
    ushort_t* xhi  = (ushort_t*)regionB;
    ushort_t* xlo  = (ushort_t*)regionB + (size_t)NN * 128;
    ushort_t* h1hi = (ushort_t*)regionB;                     // after x is dead
    ushort_t* h1lo = (ushort_t*)regionB + (size_t)NN * KP;
    float*    hgcn = (float*)regionB;                        // after h1 is dead

    const float* target = (const float*)d_in[6];

    for (int b = 0; b < 2; ++b) {
        const float* x     = (const float*)d_in[b ? 3 : 0];
        const int*   ei    = (const int*)d_in[b ? 4 : 1];
        const int*   batch = (const int*)d_in[b ? 5 : 2];
        int pb = 7 + b * 10;
        const float* gatW    = (const float*)d_in[pb + 0];
        const float* att_src = (const float*)d_in[pb + 1];
        const float* att_dst = (const float*)d_in[pb + 2];
        const float* gatb    = (const float*)d_in[pb + 3];
        const float* gcnW    = (const float*)d_in[pb + 4];
        const float* gcnb    = (const float*)d_in[pb + 5];
        const float* f1W     = (const float*)d_in[pb + 6];
        const float* f1b     = (const float*)d_in[pb + 7];
        const float* f2W     = (const float*)d_in[pb + 8];
        const float* f2b     = (const float*)d_in[pb + 9];

        // CSR
        hipLaunchKernelGGL(k_init, dim3(cdiv(NN, 256)), dim3(256), 0, stream, deg, gstart, gend);
        hipLaunchKernelGGL(k_count, dim3(cdiv(EE, 256)), dim3(256), 0, stream, ei, deg);
        hipLaunchKernelGGL(k_scan, dim3(1), dim3(1024), 0, stream, deg, offs);
        hipLaunchKernelGGL(k_prep, dim3(cdiv(NN, 256)), dim3(256), 0, stream,
                           offs, cursor, deg, dinv, batch, gstart, gend);
        hipLaunchKernelGGL(k_fill, dim3(cdiv(EPRIME, 256)), dim3(256), 0, stream, ei, cursor, csr);

        // x -> split (regionB), gatW -> transpose split
        hipLaunchKernelGGL(k_split_x, dim3(cdiv(NN * 128, 256)), dim3(256), 0, stream, x, xhi, xlo);
        hipLaunchKernelGGL(k_tsplit, dim3(cdiv(KP * 128, 256)), dim3(256), 0, stream,
                           gatW, FF, HFD, 128, KP, Bthi, Btlo);

        // h0 = x @ gatW -> split pair (regionA). ksteps=4 (Kpad=128)
        hipLaunchKernelGGL((mfma_gemm<1>), dim3(KP / 128, cdiv(NN, 128)), dim3(256), 0, stream,
                           xhi, xlo, Bthi, Btlo, 128, 128, NN, HFD, 4,
                           (float*)nullptr, 0, h0hi, h0lo, KP);

        // attention logits
        hipLaunchKernelGGL(k_att, dim3(cdiv(NN * HH, 256)), dim3(256), 0, stream,
                           h0hi, h0lo, att_src, att_dst, a_s, a_d);

        // GAT aggregate -> h1 split (regionB)
        hipLaunchKernelGGL(gat_agg, dim3(cdiv(NN, 4)), dim3(256), 0, stream,
                           h0hi, h0lo, a_s, a_d, offs, csr, gatb, h1hi, h1lo);

        // gcnW -> transpose split
        hipLaunchKernelGGL(k_tsplit, dim3(cdiv(KP * KP, 256)), dim3(256), 0, stream,
                           gcnW, HFD, HFD, KP, KP, Bthi, Btlo);

        // h2 = h1 @ gcnW -> fp32 (regionA). ksteps=36
        hipLaunchKernelGGL((mfma_gemm<0>), dim3(KP / 128, cdiv(NN, 128)), dim3(256), 0, stream,
                           h1hi, h1lo, Bthi, Btlo, KP, KP, NN, HFD, KP / 32,
                           h2f, HFD, (ushort_t*)nullptr, (ushort_t*)nullptr, 0);

        // GCN aggregate -> hgcn (regionB)
        hipLaunchKernelGGL(gcn_agg, dim3(cdiv(NN, 4)), dim3(256), 0, stream,
                           h2f, offs, csr, dinv, gcnb, hgcn);

        // pooling
        hipLaunchKernelGGL(k_pool, dim3(GG, 5), dim3(256), 0, stream, hgcn, gstart, gend, gpool);

        // fcg1: [G,2280]@[2280,1000] + bias + lrelu
        hipLaunchKernelGGL(gemm_f32, dim3(cdiv(1000, BN), cdiv(GG, BM)), dim3(256), 0, stream,
                           gpool, f1W, fc1out, GG, 1000, 2 * HFD, f1b, 0.01f);
        // fcg2
        hipLaunchKernelGGL(k_fcg2, dim3(GG), dim3(64), 0, stream,
                           fc1out, f2W, f2b, bout + (size_t)b * GG * 64);
    }

    hipLaunchKernelGGL(k_final, dim3(GG), dim3(256), 0, stream,
                       bout, bout + (size_t)GG * 64, target,
                       (const float*)d_in[27], (const float*)d_in[28],
                       (const float*)d_in[29], (const float*)d_in[30],
                       (const float*)d_in[31], (const float*)d_in[32],
                       (const float*)d_in[33], (const float*)d_in[34],
                       (float*)d_out);
}